// Round 4
// baseline (578.012 us; speedup 1.0000x reference)
//
#include <hip/hip_runtime.h>
#include <hip/hip_bf16.h>
#include <stdint.h>
#include <stddef.h>

// Problem dims
#define NB   16
#define CIN  256
#define HIN  128
#define WIN  128
#define COUT 512
#define HO   64
#define WO   64
#define HBL  129   // blurred spatial size

typedef __attribute__((ext_vector_type(8))) __bf16 bf16x8;
typedef __attribute__((ext_vector_type(4))) float  f32x4;

__device__ __forceinline__ void gld_lds16(const void* g, void* l) {
  __builtin_amdgcn_global_load_lds(
      (const __attribute__((address_space(1))) void*)g,
      (__attribute__((address_space(3))) void*)l, 16, 0, 0);
}

__device__ __forceinline__ unsigned pack_bf16(float lo, float hi) {
  __hip_bfloat16 l = __float2bfloat16(lo), h = __float2bfloat16(hi);
  unsigned short ul = *(unsigned short*)&l, uh = *(unsigned short*)&h;
  return (unsigned)ul | ((unsigned)uh << 16);
}

// ---------------------------------------------------------------------------
// Blur v2 (unchanged, passed R0/R1/R3): xb[n][i][j][c] NHWC bf16, XCD-swizzled.
// ---------------------------------------------------------------------------
__global__ __launch_bounds__(512) void blur_kernel(
    const float* __restrict__ x,
    const float* __restrict__ bk,
    __hip_bfloat16* __restrict__ xb)
{
  __shared__ __hip_bfloat16 lout[CIN * 130];  // 66560 B

  const int bid0 = blockIdx.x;
  const int bid  = (bid0 & 7) * 258 + (bid0 >> 3);  // XCD-contiguous chunks
  const int n    = bid / HBL;
  const int io   = bid % HBL;
  const int t    = threadIdx.x;
  const int wave = t >> 6;
  const int lane = t & 63;
  const int half = lane >> 5;   // channel within pair
  const int g    = lane & 31;   // 4-col group

  const float K11 = bk[5];
  float a[4], b[4];
  #pragma unroll
  for (int u = 0; u < 4; ++u) a[u] = bk[u * 4 + 1] / K11;
  #pragma unroll
  for (int v = 0; v < 4; ++v) b[v] = bk[4 + v];

  int rr[4];
  #pragma unroll
  for (int u = 0; u < 4; ++u) {
    int r = io - 2 + u;
    if (r < 0 || r >= HIN) { a[u] = 0.f; r = 0; }  // uniform: fold into tap
    rr[u] = r;
  }

  #pragma unroll 2
  for (int cb = wave * 2; cb < CIN; cb += 16) {
    const int c = cb + half;
    const float4* xr = (const float4*)(x + ((size_t)(n * CIN + c) * HIN) * WIN);
    float4 vm = {0.f, 0.f, 0.f, 0.f};
    #pragma unroll
    for (int u = 0; u < 4; ++u) {
      const float4 rv = xr[rr[u] * 32 + g];
      vm.x += a[u] * rv.x; vm.y += a[u] * rv.y;
      vm.z += a[u] * rv.z; vm.w += a[u] * rv.w;
    }
    float vmm2 = __shfl_up(vm.z, 1);    // vmid[4g-2]
    float vmm1 = __shfl_up(vm.w, 1);    // vmid[4g-1]
    float vmp4 = __shfl_down(vm.x, 1);  // vmid[4g+4]
    if (g == 0)  { vmm2 = 0.f; vmm1 = 0.f; }
    if (g == 31) { vmp4 = 0.f; }
    const float o0 = b[0]*vmm2 + b[1]*vmm1 + b[2]*vm.x + b[3]*vm.y;
    const float o1 = b[0]*vmm1 + b[1]*vm.x + b[2]*vm.y + b[3]*vm.z;
    const float o2 = b[0]*vm.x + b[1]*vm.y + b[2]*vm.z + b[3]*vm.w;
    const float o3 = b[0]*vm.y + b[1]*vm.z + b[2]*vm.w + b[3]*vmp4;
    unsigned* dst = (unsigned*)&lout[c * 130 + 4 * g];
    dst[0] = pack_bf16(o0, o1);
    dst[1] = pack_bf16(o2, o3);
    if (g == 31)
      lout[c * 130 + 128] = __float2bfloat16(b[0]*vm.z + b[1]*vm.w);
  }

  __syncthreads();

  const size_t obase = ((size_t)(n * HBL + io)) * HBL * CIN;
  for (int e = t; e < 65 * 64; e += 512) {
    const int jp = e >> 6;
    const int l  = e & 63;
    const unsigned r0 = *(const unsigned*)&lout[(4*l + 0) * 130 + 2*jp];
    const unsigned r1 = *(const unsigned*)&lout[(4*l + 1) * 130 + 2*jp];
    const unsigned r2 = *(const unsigned*)&lout[(4*l + 2) * 130 + 2*jp];
    const unsigned r3 = *(const unsigned*)&lout[(4*l + 3) * 130 + 2*jp];
    uint2 s0, s1;
    s0.x = (r0 & 0xffffu) | (r1 << 16);
    s0.y = (r2 & 0xffffu) | (r3 << 16);
    s1.x = (r0 >> 16) | (r1 & 0xffff0000u);
    s1.y = (r2 >> 16) | (r3 & 0xffff0000u);
    *(uint2*)&xb[obase + (size_t)(2*jp) * CIN + 4*l] = s0;
    if (jp < 64)
      *(uint2*)&xb[obase + (size_t)(2*jp + 1) * CIN + 4*l] = s1;
  }
}

// ---------------------------------------------------------------------------
// Weight prep (unchanged): wt[tap][o][c] = bf16(w[o][c][kh][kw])
// ---------------------------------------------------------------------------
__global__ __launch_bounds__(256) void wprep_kernel(
    const float* __restrict__ w,
    __hip_bfloat16* __restrict__ wt)
{
  const int idx = blockIdx.x * 256 + threadIdx.x;
  if (idx >= 9 * COUT * CIN) return;
  const int c   = idx & (CIN - 1);
  const int o   = (idx >> 8) & (COUT - 1);
  const int tap = idx >> 17;
  wt[idx] = __float2bfloat16(w[(o * CIN + c) * 9 + tap]);
}

// ---------------------------------------------------------------------------
// Implicit GEMM v3: 256x256 tile, BK=32, 4-slot LDS ring, m201-style 2-phase
// schedule. 72 K-tiles. 8 waves = 2(o-half:128) x 4(px-quarter:64).
// Per tile: phase A = {read aw0-3,bx0-3 (8 ds_read) + stage(kt+3) (4 gld),
// bar, lgkm0, 16 MFMA, bar}; phase B = {read aw4-7 (4 ds_read), vmcnt(8),
// bar, lgkm0, 16 MFMA, bar}. Reads sit BEFORE their barrier so latency hides
// under barrier stagger + other waves' MFMA (setprio arbitration). vmcnt(8)
// (2 newest tiles outstanding) before phase-B bar guarantees tile kt+1 is
// cross-wave resident for next iteration's pre-barrier reads. Max live frags
// ~8 -> no VGPR growth (128 arch + 128 acc = full file at 2 waves/SIMD).
// Swizzle unchanged: g3 = ((r&1)<<2 | q) ^ ((r>>1)&7), inverse folded into
// per-lane GLOBAL source addresses (LDS dest linear).
// ---------------------------------------------------------------------------
__global__ __launch_bounds__(512, 2) void gemm_kernel(
    const __hip_bfloat16* __restrict__ xb,    // [16][129][129][256]
    const __hip_bfloat16* __restrict__ wt,    // [9][512][256]
    const float* __restrict__ bias,           // [512]
    float* __restrict__ y)                    // [16][512][64][64]
{
  __shared__ __align__(16) char lds[4 * 32768];   // 128 KiB ring

  const int t    = threadIdx.x;
  const int wave = t >> 6;
  const int lane = t & 63;
  const int bid0 = blockIdx.x;
  const int bid  = (bid0 & 7) * 64 + (bid0 >> 3);  // XCD swizzle (512 = 8*64)
  const int nb   = bid & 1;    // 2 N-blocks (adjacent -> same XCD L2)
  const int mb   = bid >> 1;   // 256 M-blocks
  const int o0   = nb * 256;
  const int p0   = mb * 256;   // 256 pixels: rows h0..h0+3 x w=0..63 of imgn
  const int imgn = p0 >> 12;
  const int h0   = (p0 >> 6) & 63;

  const int wo  = wave >> 2;   // o-half (128 rows)
  const int wp  = wave & 3;    // px-quarter (64 rows)
  const int q   = lane >> 4;
  const int m16 = lane & 15;

  // ---- staging constants: 2 issues each for W and X per tile per wave.
  long xg[2], wg[2];
  int  ldsoff[2];
  #pragma unroll
  for (int s = 0; s < 2; ++s) {
    const int ia = wave * 2 + s;
    const int Lr = ia * 8 + (lane >> 3);
    const int g3 = (lane & 7) ^ (Lr & 7);
    const int r  = 2 * Lr + (g3 >> 2);
    const int cq = (g3 & 3) * 8;
    const int hh = h0 + (r >> 6);
    const int ww = r & 63;
    xg[s] = ((long)(imgn * HBL + 2 * hh) * HBL + 2 * ww) * CIN + cq;
    wg[s] = (long)(o0 + r) * CIN + cq;
    ldsoff[s] = ia * 1024;   // wave-uniform
  }

  // ---- fragment read offsets (bytes within a slot region)
  int aoff[8];   // W rows: wo*128 + of*16 + m16
  #pragma unroll
  for (int of = 0; of < 8; ++of) {
    const int r  = wo * 128 + of * 16 + m16;
    const int g3 = (((r & 1) << 2) | q) ^ ((r >> 1) & 7);
    aoff[of] = (r >> 1) * 128 + g3 * 16;
  }
  int boff[4];   // X rows: wp*64 + pf*16 + m16
  #pragma unroll
  for (int pf = 0; pf < 4; ++pf) {
    const int r  = wp * 64 + pf * 16 + m16;
    const int g3 = (((r & 1) << 2) | q) ^ ((r >> 1) & 7);
    boff[pf] = (r >> 1) * 128 + g3 * 16;
  }

  f32x4 acc[8][4];
  #pragma unroll
  for (int of = 0; of < 8; ++of)
    #pragma unroll
    for (int pf = 0; pf < 4; ++pf)
      acc[of][pf] = (f32x4){0.f, 0.f, 0.f, 0.f};

  // K-tile kt: tap = kt>>3, cb = (kt&7)*32; slot = kt&3.
  auto stage = [&](int kt) {
    const int  slot = kt & 3;
    const int  tap  = kt >> 3;
    const int  cb   = (kt & 7) * 32;
    const long xoff = (long)((tap / 3) * HBL + (tap % 3)) * CIN + cb;
    const long woff = (long)tap * (COUT * CIN) + cb;
    char* sb = &lds[slot * 32768];
    #pragma unroll
    for (int s = 0; s < 2; ++s) {
      gld_lds16(wt + woff + wg[s], sb + ldsoff[s]);           // W: [0,16K)
      gld_lds16(xb + xoff + xg[s], sb + 16384 + ldsoff[s]);   // X: [16K,32K)
    }
  };

  // prologue: 3 tiles in flight; tile 0 resident + visible before loop
  stage(0); stage(1); stage(2);
  asm volatile("s_waitcnt vmcnt(8)" ::: "memory");
  __builtin_amdgcn_s_barrier();

  for (int kt = 0; kt < 72; ++kt) {
    const char* sb = &lds[(kt & 3) * 32768];
    __builtin_amdgcn_sched_barrier(0);   // reads stay below prev barrier

    // ---------------- phase A: of 0..3 ----------------
    bf16x8 aw0[4], bx[4];
    #pragma unroll
    for (int i = 0; i < 4; ++i)
      aw0[i] = *(const bf16x8*)(sb + aoff[i]);
    #pragma unroll
    for (int i = 0; i < 4; ++i)
      bx[i] = *(const bf16x8*)(sb + 16384 + boff[i]);
    if (kt < 69) stage(kt + 3);          // slot (kt+3)&3 = (kt-1)&3: safe
    __builtin_amdgcn_s_barrier();
    asm volatile("s_waitcnt lgkmcnt(0)" ::: "memory");
    __builtin_amdgcn_sched_barrier(0);   // MFMA can't hoist above lgkm0
    __builtin_amdgcn_s_setprio(1);
    #pragma unroll
    for (int of = 0; of < 4; ++of)
      #pragma unroll
      for (int pf = 0; pf < 4; ++pf)
        acc[of][pf] = __builtin_amdgcn_mfma_f32_16x16x32_bf16(
            aw0[of], bx[pf], acc[of][pf], 0, 0, 0);
    __builtin_amdgcn_s_setprio(0);
    __builtin_amdgcn_sched_barrier(0);   // MFMA can't sink below barrier
    __builtin_amdgcn_s_barrier();
    __builtin_amdgcn_sched_barrier(0);

    // ---------------- phase B: of 4..7 ----------------
    bf16x8 aw1[4];
    #pragma unroll
    for (int i = 0; i < 4; ++i)
      aw1[i] = *(const bf16x8*)(sb + aoff[4 + i]);
    // counted wait: all but 2 newest tiles done -> tile kt+1 resident
    if (kt <= 68)      asm volatile("s_waitcnt vmcnt(8)" ::: "memory");
    else if (kt == 69) asm volatile("s_waitcnt vmcnt(4)" ::: "memory");
    else               asm volatile("s_waitcnt vmcnt(0)" ::: "memory");
    __builtin_amdgcn_s_barrier();
    asm volatile("s_waitcnt lgkmcnt(0)" ::: "memory");
    __builtin_amdgcn_sched_barrier(0);
    __builtin_amdgcn_s_setprio(1);
    #pragma unroll
    for (int of = 0; of < 4; ++of)
      #pragma unroll
      for (int pf = 0; pf < 4; ++pf)
        acc[4 + of][pf] = __builtin_amdgcn_mfma_f32_16x16x32_bf16(
            aw1[of], bx[pf], acc[4 + of][pf], 0, 0, 0);
    __builtin_amdgcn_s_setprio(0);
    __builtin_amdgcn_sched_barrier(0);
    __builtin_amdgcn_s_barrier();
  }

  // ---- epilogue: D col = px (lane&15), row = o (q*4 + rg); scale + bias
  const float scale = 1.0f / 48.0f;
  #pragma unroll
  for (int of = 0; of < 8; ++of) {
    const int o = o0 + wo * 128 + of * 16 + q * 4;
    #pragma unroll
    for (int pf = 0; pf < 4; ++pf) {
      const int p  = p0 + wp * 64 + pf * 16 + m16;
      const int n  = p >> 12;
      const int hh = (p >> 6) & 63;
      const int ww = p & 63;
      const size_t obase = ((size_t)(n * COUT + o) * HO + hh) * WO + ww;
      #pragma unroll
      for (int rg = 0; rg < 4; ++rg) {
        const float v = acc[of][pf][rg] * scale + bias[o + rg];
        y[obase + (size_t)rg * (HO * WO)] = v;
      }
    }
  }
}

// ---------------------------------------------------------------------------
extern "C" void kernel_launch(void* const* d_in, const int* in_sizes, int n_in,
                              void* d_out, int out_size, void* d_ws, size_t ws_size,
                              hipStream_t stream) {
  const float* x  = (const float*)d_in[0];
  const float* w  = (const float*)d_in[1];
  const float* bs = (const float*)d_in[2];
  const float* bk = (const float*)d_in[3];
  float* y = (float*)d_out;

  // workspace: xb (NHWC blurred bf16, 136.3 MB) + wt (2.4 MB)
  __hip_bfloat16* xb = (__hip_bfloat16*)d_ws;
  __hip_bfloat16* wt = (__hip_bfloat16*)((char*)d_ws +
                       (size_t)NB * HBL * HBL * CIN * sizeof(__hip_bfloat16));

  hipLaunchKernelGGL(blur_kernel, dim3(NB * HBL), dim3(512), 0, stream, x, bk, xb);
  hipLaunchKernelGGL(wprep_kernel, dim3((9 * COUT * CIN + 255) / 256), dim3(256), 0, stream, w, wt);
  hipLaunchKernelGGL(gemm_kernel, dim3(256 * 2), dim3(512), 0, stream,
                     xb, wt, bs, y);
}

// Round 5
// 562.389 us; speedup vs baseline: 1.0278x; 1.0278x over previous
//
#include <hip/hip_runtime.h>
#include <hip/hip_bf16.h>
#include <stdint.h>
#include <stddef.h>

// Problem dims
#define NB   16
#define CIN  256
#define HIN  128
#define WIN  128
#define COUT 512
#define HO   64
#define WO   64
#define HBL  129   // blurred spatial size

typedef __attribute__((ext_vector_type(8))) __bf16 bf16x8;
typedef __attribute__((ext_vector_type(4))) float  f32x4;

__device__ __forceinline__ void gld_lds16(const void* g, void* l) {
  __builtin_amdgcn_global_load_lds(
      (const __attribute__((address_space(1))) void*)g,
      (__attribute__((address_space(3))) void*)l, 16, 0, 0);
}

__device__ __forceinline__ unsigned pack_bf16(float lo, float hi) {
  __hip_bfloat16 l = __float2bfloat16(lo), h = __float2bfloat16(hi);
  unsigned short ul = *(unsigned short*)&l, uh = *(unsigned short*)&h;
  return (unsigned)ul | ((unsigned)uh << 16);
}

// ---------------------------------------------------------------------------
// Blur v2 (unchanged, passed R0/R1/R3/R4): xb NHWC bf16, XCD-swizzled grid.
// ---------------------------------------------------------------------------
__global__ __launch_bounds__(512) void blur_kernel(
    const float* __restrict__ x,
    const float* __restrict__ bk,
    __hip_bfloat16* __restrict__ xb)
{
  __shared__ __hip_bfloat16 lout[CIN * 130];  // 66560 B

  const int bid0 = blockIdx.x;
  const int bid  = (bid0 & 7) * 258 + (bid0 >> 3);  // XCD-contiguous chunks
  const int n    = bid / HBL;
  const int io   = bid % HBL;
  const int t    = threadIdx.x;
  const int wave = t >> 6;
  const int lane = t & 63;
  const int half = lane >> 5;   // channel within pair
  const int g    = lane & 31;   // 4-col group

  const float K11 = bk[5];
  float a[4], b[4];
  #pragma unroll
  for (int u = 0; u < 4; ++u) a[u] = bk[u * 4 + 1] / K11;
  #pragma unroll
  for (int v = 0; v < 4; ++v) b[v] = bk[4 + v];

  int rr[4];
  #pragma unroll
  for (int u = 0; u < 4; ++u) {
    int r = io - 2 + u;
    if (r < 0 || r >= HIN) { a[u] = 0.f; r = 0; }  // uniform: fold into tap
    rr[u] = r;
  }

  #pragma unroll 2
  for (int cb = wave * 2; cb < CIN; cb += 16) {
    const int c = cb + half;
    const float4* xr = (const float4*)(x + ((size_t)(n * CIN + c) * HIN) * WIN);
    float4 vm = {0.f, 0.f, 0.f, 0.f};
    #pragma unroll
    for (int u = 0; u < 4; ++u) {
      const float4 rv = xr[rr[u] * 32 + g];
      vm.x += a[u] * rv.x; vm.y += a[u] * rv.y;
      vm.z += a[u] * rv.z; vm.w += a[u] * rv.w;
    }
    float vmm2 = __shfl_up(vm.z, 1);    // vmid[4g-2]
    float vmm1 = __shfl_up(vm.w, 1);    // vmid[4g-1]
    float vmp4 = __shfl_down(vm.x, 1);  // vmid[4g+4]
    if (g == 0)  { vmm2 = 0.f; vmm1 = 0.f; }
    if (g == 31) { vmp4 = 0.f; }
    const float o0 = b[0]*vmm2 + b[1]*vmm1 + b[2]*vm.x + b[3]*vm.y;
    const float o1 = b[0]*vmm1 + b[1]*vm.x + b[2]*vm.y + b[3]*vm.z;
    const float o2 = b[0]*vm.x + b[1]*vm.y + b[2]*vm.z + b[3]*vm.w;
    const float o3 = b[0]*vm.y + b[1]*vm.z + b[2]*vm.w + b[3]*vmp4;
    unsigned* dst = (unsigned*)&lout[c * 130 + 4 * g];
    dst[0] = pack_bf16(o0, o1);
    dst[1] = pack_bf16(o2, o3);
    if (g == 31)
      lout[c * 130 + 128] = __float2bfloat16(b[0]*vm.z + b[1]*vm.w);
  }

  __syncthreads();

  const size_t obase = ((size_t)(n * HBL + io)) * HBL * CIN;
  for (int e = t; e < 65 * 64; e += 512) {
    const int jp = e >> 6;
    const int l  = e & 63;
    const unsigned r0 = *(const unsigned*)&lout[(4*l + 0) * 130 + 2*jp];
    const unsigned r1 = *(const unsigned*)&lout[(4*l + 1) * 130 + 2*jp];
    const unsigned r2 = *(const unsigned*)&lout[(4*l + 2) * 130 + 2*jp];
    const unsigned r3 = *(const unsigned*)&lout[(4*l + 3) * 130 + 2*jp];
    uint2 s0, s1;
    s0.x = (r0 & 0xffffu) | (r1 << 16);
    s0.y = (r2 & 0xffffu) | (r3 << 16);
    s1.x = (r0 >> 16) | (r1 & 0xffff0000u);
    s1.y = (r2 >> 16) | (r3 & 0xffff0000u);
    *(uint2*)&xb[obase + (size_t)(2*jp) * CIN + 4*l] = s0;
    if (jp < 64)
      *(uint2*)&xb[obase + (size_t)(2*jp + 1) * CIN + 4*l] = s1;
  }
}

// ---------------------------------------------------------------------------
// Weight prep (unchanged): wt[tap][o][c] = bf16(w[o][c][kh][kw])
// ---------------------------------------------------------------------------
__global__ __launch_bounds__(256) void wprep_kernel(
    const float* __restrict__ w,
    __hip_bfloat16* __restrict__ wt)
{
  const int idx = blockIdx.x * 256 + threadIdx.x;
  if (idx >= 9 * COUT * CIN) return;
  const int c   = idx & (CIN - 1);
  const int o   = (idx >> 8) & (COUT - 1);
  const int tap = idx >> 17;
  wt[idx] = __float2bfloat16(w[(o * CIN + c) * 9 + tap]);
}

// ---------------------------------------------------------------------------
// Implicit GEMM v4: 256x256 tile, BK=32, 4-slot LDS ring, CROSS-TILE FRAGMENT
// PIPELINE. 72 K-tiles, 8 waves = 2(o-half:128) x 4(px-quarter:64).
// R4 lesson: lockstep phases serialize LDS-read (857cy) and MFMA (1242cy)
// per tile -> 2780cy wall. v4: one barrier per tile; each iteration issues
// ds_reads for tile kt+1 (into the OTHER frag buffer) and the 32 MFMAs of
// tile kt with NO fence between them -> reads hide under MFMA on separate
// pipes within the same wave. lgkm(0)+vmcnt(4) only at iteration end.
// Residency: vmcnt(4) leaves only tile kt+3 outstanding -> tiles <= kt+2
// resident after the barrier; next iteration reads tile kt+2. Ring WAR:
// stage(kt+3) overwrites slot of tile kt-1, whose frag reads lgkm-completed
// 2 barriers ago. Frag addressing: g3 swizzle is of/pf-invariant (proof:
// (r>>1)&7 and r&1 depend only on m16) -> one base + of*1024 immediates.
// Frag double-buffer A/B with static names (rule #20); pair-unrolled loop.
// ---------------------------------------------------------------------------
__global__ __launch_bounds__(512, 2) void gemm_kernel(
    const __hip_bfloat16* __restrict__ xb,    // [16][129][129][256]
    const __hip_bfloat16* __restrict__ wt,    // [9][512][256]
    const float* __restrict__ bias,           // [512]
    float* __restrict__ y)                    // [16][512][64][64]
{
  __shared__ __align__(16) char lds[4 * 32768];   // 128 KiB ring

  const int t    = threadIdx.x;
  const int wave = t >> 6;
  const int lane = t & 63;
  const int bid0 = blockIdx.x;
  const int bid  = (bid0 & 7) * 64 + (bid0 >> 3);  // XCD swizzle (512 = 8*64)
  const int nb   = bid & 1;    // 2 N-blocks (adjacent -> same XCD L2)
  const int mb   = bid >> 1;   // 256 M-blocks
  const int o0   = nb * 256;
  const int p0   = mb * 256;   // 256 pixels: rows h0..h0+3 x w=0..63 of imgn
  const int imgn = p0 >> 12;
  const int h0   = (p0 >> 6) & 63;

  const int wo  = wave >> 2;   // o-half (128 rows)
  const int wp  = wave & 3;    // px-quarter (64 rows)
  const int q   = lane >> 4;
  const int m16 = lane & 15;

  // ---- staging constants: 2 issues each for W and X per tile per wave.
  long xg[2], wg[2];
  int  ldsoff[2];
  #pragma unroll
  for (int s = 0; s < 2; ++s) {
    const int ia = wave * 2 + s;
    const int Lr = ia * 8 + (lane >> 3);
    const int g3 = (lane & 7) ^ (Lr & 7);
    const int r  = 2 * Lr + (g3 >> 2);
    const int cq = (g3 & 3) * 8;
    const int hh = h0 + (r >> 6);
    const int ww = r & 63;
    xg[s] = ((long)(imgn * HBL + 2 * hh) * HBL + 2 * ww) * CIN + cq;
    wg[s] = (long)(o0 + r) * CIN + cq;
    ldsoff[s] = ia * 1024;   // wave-uniform
  }

  // ---- fragment base offsets; per-of/pf deltas are compile-time (*1024)
  const int g3f   = (((m16 & 1) << 2) | q) ^ ((m16 >> 1) & 7);
  const int abase = ((wo * 128 + m16) >> 1) * 128 + g3f * 16;
  const int bbase = ((wp * 64  + m16) >> 1) * 128 + g3f * 16;

  f32x4 acc[8][4];
  #pragma unroll
  for (int of = 0; of < 8; ++of)
    #pragma unroll
    for (int pf = 0; pf < 4; ++pf)
      acc[of][pf] = (f32x4){0.f, 0.f, 0.f, 0.f};

  // K-tile kt: tap = kt>>3, cb = (kt&7)*32; slot = kt&3.
  auto stage = [&](int kt) {
    const int  slot = kt & 3;
    const int  tap  = kt >> 3;
    const int  cb   = (kt & 7) * 32;
    const long xoff = (long)((tap / 3) * HBL + (tap % 3)) * CIN + cb;
    const long woff = (long)tap * (COUT * CIN) + cb;
    char* sb = &lds[slot * 32768];
    #pragma unroll
    for (int s = 0; s < 2; ++s) {
      gld_lds16(wt + woff + wg[s], sb + ldsoff[s]);           // W: [0,16K)
      gld_lds16(xb + xoff + xg[s], sb + 16384 + ldsoff[s]);   // X: [16K,32K)
    }
  };

  auto read_frags = [&](bf16x8 (&aw)[8], bf16x8 (&bx)[4], const char* sb) {
    #pragma unroll
    for (int i = 0; i < 8; ++i)
      aw[i] = *(const bf16x8*)(sb + abase + i * 1024);
    #pragma unroll
    for (int i = 0; i < 4; ++i)
      bx[i] = *(const bf16x8*)(sb + 16384 + bbase + i * 1024);
  };

  auto mfma_tile = [&](const bf16x8 (&aw)[8], const bf16x8 (&bx)[4]) {
    __builtin_amdgcn_s_setprio(1);
    #pragma unroll
    for (int of = 0; of < 8; ++of)
      #pragma unroll
      for (int pf = 0; pf < 4; ++pf)
        acc[of][pf] = __builtin_amdgcn_mfma_f32_16x16x32_bf16(
            aw[of], bx[pf], acc[of][pf], 0, 0, 0);
    __builtin_amdgcn_s_setprio(0);
  };

  bf16x8 awA[8], bxA[4], awB[8], bxB[4];

  // body: MFMA(kt) on CUR while reading frags(kt+1) into NXT; 1 barrier.
  auto body = [&](int kt, bf16x8 (&cAW)[8], bf16x8 (&cBX)[4],
                  bf16x8 (&nAW)[8], bf16x8 (&nBX)[4]) {
    if (kt <= 68) stage(kt + 3);
    if (kt < 71)
      read_frags(nAW, nBX, &lds[((kt + 1) & 3) * 32768]);
    mfma_tile(cAW, cBX);                  // no fence: co-issues with reads
    asm volatile("s_waitcnt lgkmcnt(0)" ::: "memory");
    __builtin_amdgcn_sched_barrier(0);    // next MFMA can't hoist above wait
    if (kt <= 68)      asm volatile("s_waitcnt vmcnt(4)" ::: "memory");
    else if (kt == 69) asm volatile("s_waitcnt vmcnt(0)" ::: "memory");
    __builtin_amdgcn_s_barrier();
    __builtin_amdgcn_sched_barrier(0);    // next reads can't hoist above bar
  };

  // prologue: 3 tiles in flight; tiles 0,1 resident; frags(0) in A
  stage(0); stage(1); stage(2);
  asm volatile("s_waitcnt vmcnt(4)" ::: "memory");
  __builtin_amdgcn_s_barrier();
  __builtin_amdgcn_sched_barrier(0);
  read_frags(awA, bxA, &lds[0]);
  asm volatile("s_waitcnt lgkmcnt(0)" ::: "memory");
  __builtin_amdgcn_sched_barrier(0);

  for (int ktp = 0; ktp < 72; ktp += 2) {
    body(ktp,     awA, bxA, awB, bxB);
    body(ktp + 1, awB, bxB, awA, bxA);
  }

  // ---- epilogue: D col = px (lane&15), row = o (q*4 + rg); scale + bias
  const float scale = 1.0f / 48.0f;
  #pragma unroll
  for (int of = 0; of < 8; ++of) {
    const int o = o0 + wo * 128 + of * 16 + q * 4;
    #pragma unroll
    for (int pf = 0; pf < 4; ++pf) {
      const int p  = p0 + wp * 64 + pf * 16 + m16;
      const int n  = p >> 12;
      const int hh = (p >> 6) & 63;
      const int ww = p & 63;
      const size_t obase = ((size_t)(n * COUT + o) * HO + hh) * WO + ww;
      #pragma unroll
      for (int rg = 0; rg < 4; ++rg) {
        const float v = acc[of][pf][rg] * scale + bias[o + rg];
        y[obase + (size_t)rg * (HO * WO)] = v;
      }
    }
  }
}

// ---------------------------------------------------------------------------
extern "C" void kernel_launch(void* const* d_in, const int* in_sizes, int n_in,
                              void* d_out, int out_size, void* d_ws, size_t ws_size,
                              hipStream_t stream) {
  const float* x  = (const float*)d_in[0];
  const float* w  = (const float*)d_in[1];
  const float* bs = (const float*)d_in[2];
  const float* bk = (const float*)d_in[3];
  float* y = (float*)d_out;

  // workspace: xb (NHWC blurred bf16, 136.3 MB) + wt (2.4 MB)
  __hip_bfloat16* xb = (__hip_bfloat16*)d_ws;
  __hip_bfloat16* wt = (__hip_bfloat16*)((char*)d_ws +
                       (size_t)NB * HBL * HBL * CIN * sizeof(__hip_bfloat16));

  hipLaunchKernelGGL(blur_kernel, dim3(NB * HBL), dim3(512), 0, stream, x, bk, xb);
  hipLaunchKernelGGL(wprep_kernel, dim3((9 * COUT * CIN + 255) / 256), dim3(256), 0, stream, w, wt);
  hipLaunchKernelGGL(gemm_kernel, dim3(256 * 2), dim3(512), 0, stream,
                     xb, wt, bs, y);
}